// Round 5
// baseline (583.088 us; speedup 1.0000x reference)
//
#include <hip/hip_runtime.h>

#define N_NODES 100000
#define N_EDGES 3200000
#define EPS 1e-5f
#define NODE_BLOCKS 391   // ceil(100000/256)

// ---- workspace layout (bytes) ----
#define OFF_STATS  0          // 8 doubles (bn sums)            [zeroed]
#define OFF_CNT    1024       // int[100000] in-degree          [zeroed]
#define OFF_ROWPTR 401280     // int[100001]
#define OFF_INVCNT 801536     // float[100000]
#define OFF_AGG1   1201536    // float2[100000] encoder node out
#define OFF_XN     2001536    // float4[100000] normalized x
#define OFF_RANK   3601536    // int[3200000] rank within dst
#define OFF_BSUM   16401536   // int[391]
#define OFF_BOFF   16403456   // int[391]
#define OFF_W1T    16405504   // transposed weights
#define OFF_W2T    16406528
#define OFF_V1T    16410624
#define OFF_V2T    16411136
#define OFF_H      16416768   // CSR-ordered edge outputs; he(float2)/hd(float4) aliased
// total ≈ 67.6 MB

__global__ __launch_bounds__(256) void k_bn_stats(const float* __restrict__ x,
                                                  double* __restrict__ stats) {
    int i = blockIdx.x * 256 + threadIdx.x;
    float4 v = make_float4(0.f, 0.f, 0.f, 0.f);
    if (i < N_NODES) v = ((const float4*)x)[i];
    double a[8];
    a[0] = v.x; a[1] = v.y; a[2] = v.z; a[3] = v.w;
    a[4] = (double)v.x * v.x; a[5] = (double)v.y * v.y;
    a[6] = (double)v.z * v.z; a[7] = (double)v.w * v.w;
    #pragma unroll
    for (int off = 32; off > 0; off >>= 1) {
        #pragma unroll
        for (int j = 0; j < 8; j++) a[j] += __shfl_down(a[j], off);
    }
    __shared__ double smem[4][8];
    int wave = threadIdx.x >> 6;
    int lane = threadIdx.x & 63;
    if (lane == 0) {
        #pragma unroll
        for (int j = 0; j < 8; j++) smem[wave][j] = a[j];
    }
    __syncthreads();
    if (threadIdx.x == 0) {
        #pragma unroll
        for (int j = 0; j < 8; j++) {
            double t = smem[0][j] + smem[1][j] + smem[2][j] + smem[3][j];
            atomicAdd(&stats[j], t);
        }
    }
}

__global__ __launch_bounds__(256) void k_normalize(const float* __restrict__ x,
                                                   const double* __restrict__ stats,
                                                   const float* __restrict__ bn_w,
                                                   const float* __restrict__ bn_b,
                                                   float* __restrict__ xn) {
    int i = blockIdx.x * 256 + threadIdx.x;
    if (i >= N_NODES) return;
    const double inv_n = 1.0 / (double)N_NODES;
    float mu[4], sc[4], sh[4];
    #pragma unroll
    for (int d = 0; d < 4; d++) {
        double m  = stats[d] * inv_n;
        double vr = stats[4 + d] * inv_n - m * m;
        float rs  = (float)(1.0 / sqrt(vr + (double)EPS));
        mu[d] = (float)m;
        sc[d] = rs * bn_w[d];
        sh[d] = bn_b[d];
    }
    float4 v = ((const float4*)x)[i];
    float4 o;
    o.x = (v.x - mu[0]) * sc[0] + sh[0];
    o.y = (v.y - mu[1]) * sc[1] + sh[1];
    o.z = (v.z - mu[2]) * sc[2] + sh[2];
    o.w = (v.w - mu[3]) * sc[3] + sh[3];
    ((float4*)xn)[i] = o;
}

// transpose weights so the streaming-j MLP form reads contiguous scalar rows
__global__ __launch_bounds__(1024) void k_prep(const float* __restrict__ ew1,
                                               const float* __restrict__ ew2,
                                               const float* __restrict__ dw1,
                                               const float* __restrict__ dw2,
                                               float* __restrict__ w1t,
                                               float* __restrict__ w2t,
                                               float* __restrict__ v1t,
                                               float* __restrict__ v2t) {
    int t = threadIdx.x;
    { int j = t >> 5, k = t & 31; w2t[j * 32 + k] = ew2[k * 32 + j]; }
    { int j = t >> 5, k = t & 31; v2t[j * 32 + k] = dw2[k * 32 + j]; }
    if (t < 256) { int j = t >> 3, k = t & 7; w1t[j * 8 + k] = ew1[k * 32 + j]; }
    if (t < 128) { int j = t >> 2, k = t & 3; v1t[j * 4 + k] = dw1[k * 32 + j]; }
}

// rank[e] = position of edge e among edges sharing its dst; cnt[d] = in-degree
__global__ __launch_bounds__(256) void k_rank(const int* __restrict__ ei,
                                              int* __restrict__ cnt,
                                              int* __restrict__ rank) {
    int e = blockIdx.x * 256 + threadIdx.x;
    if (e >= N_EDGES) return;
    int d = ei[N_EDGES + e];
    rank[e] = atomicAdd(&cnt[d], 1);
}

// scan phase A: per-block sums of cnt; also invcnt
__global__ __launch_bounds__(256) void k_scan_part(const int* __restrict__ cnt,
                                                   int* __restrict__ bsum,
                                                   float* __restrict__ invcnt) {
    int i = blockIdx.x * 256 + threadIdx.x;
    int c = (i < N_NODES) ? cnt[i] : 0;
    if (i < N_NODES) invcnt[i] = 1.0f / (float)(c > 1 ? c : 1);
    int s = c;
    #pragma unroll
    for (int off = 32; off > 0; off >>= 1) s += __shfl_down(s, off);
    __shared__ int wsum[4];
    int wave = threadIdx.x >> 6, lane = threadIdx.x & 63;
    if (lane == 0) wsum[wave] = s;
    __syncthreads();
    if (threadIdx.x == 0) bsum[blockIdx.x] = wsum[0] + wsum[1] + wsum[2] + wsum[3];
}

// scan phase B: single small block scans 391 block sums -> block offsets + total
__global__ __launch_bounds__(512) void k_scan_top(const int* __restrict__ bsum,
                                                  int* __restrict__ boff,
                                                  int* __restrict__ rowptr) {
    __shared__ int sm[512];
    int t = threadIdx.x;
    int v = (t < NODE_BLOCKS) ? bsum[t] : 0;
    sm[t] = v;
    __syncthreads();
    for (int off = 1; off < 512; off <<= 1) {
        int u = (t >= off) ? sm[t - off] : 0;
        __syncthreads();
        sm[t] += u;
        __syncthreads();
    }
    if (t < NODE_BLOCKS) boff[t] = (t == 0) ? 0 : sm[t - 1];
    if (t == 511) rowptr[N_NODES] = sm[511];
}

// scan phase C: in-block exclusive scan + block offset -> rowptr
__global__ __launch_bounds__(256) void k_scan_local(const int* __restrict__ cnt,
                                                    const int* __restrict__ boff,
                                                    int* __restrict__ rowptr) {
    int i = blockIdx.x * 256 + threadIdx.x;
    int c = (i < N_NODES) ? cnt[i] : 0;
    int lane = threadIdx.x & 63;
    int wave = threadIdx.x >> 6;
    int x = c;
    #pragma unroll
    for (int off = 1; off < 64; off <<= 1) {
        int u = __shfl_up(x, off);
        if (lane >= off) x += u;
    }
    __shared__ int wsum[4];
    if (lane == 63) wsum[wave] = x;
    __syncthreads();
    int wo = 0;
    #pragma unroll
    for (int w = 0; w < 4; w++) if (w < wave) wo += wsum[w];
    if (i < N_NODES) rowptr[i] = boff[blockIdx.x] + wo + (x - c);
}

// Encoder EdgeConv per-edge MLP: 8 -> 32 -> 32 -> 2, relu x3.
// TWO edges per thread: each weight scalar feeds 2 FMAs (halves wait/FMA ratio).
__global__ __launch_bounds__(256, 4) void k_enc_edge(const float* __restrict__ xn,
                                                     const int* __restrict__ ei,
                                                     const int* __restrict__ rowptr,
                                                     const int* __restrict__ rank,
                                                     float2* __restrict__ he,
                                                     const float* __restrict__ w1t,
                                                     const float* __restrict__ b1,
                                                     const float* __restrict__ w2t,
                                                     const float* __restrict__ b2,
                                                     const float* __restrict__ w3,
                                                     const float* __restrict__ b3) {
    int t = blockIdx.x * 256 + threadIdx.x;
    int e0 = 2 * t;
    if (e0 >= N_EDGES) return;   // N_EDGES even -> e0+1 also valid
    int2 ss = *(const int2*)&ei[e0];
    int2 dd = *(const int2*)&ei[N_EDGES + e0];
    int2 rk = *(const int2*)&rank[e0];
    float4 xiA = ((const float4*)xn)[dd.x];
    float4 xjA = ((const float4*)xn)[ss.x];
    float4 xiB = ((const float4*)xn)[dd.y];
    float4 xjB = ((const float4*)xn)[ss.y];
    float inA[8], inB[8];
    inA[0] = xiA.x; inA[1] = xiA.y; inA[2] = xiA.z; inA[3] = xiA.w;
    inA[4] = xjA.x - xiA.x; inA[5] = xjA.y - xiA.y; inA[6] = xjA.z - xiA.z; inA[7] = xjA.w - xiA.w;
    inB[0] = xiB.x; inB[1] = xiB.y; inB[2] = xiB.z; inB[3] = xiB.w;
    inB[4] = xjB.x - xiB.x; inB[5] = xjB.y - xiB.y; inB[6] = xjB.z - xiB.z; inB[7] = xjB.w - xiB.w;

    float h1A[32], h1B[32];
    #pragma unroll
    for (int j = 0; j < 32; j++) {
        float a = b1[j], b = a;
        #pragma unroll
        for (int k = 0; k < 8; k++) {
            float w = w1t[j * 8 + k];
            a = fmaf(inA[k], w, a);
            b = fmaf(inB[k], w, b);
        }
        h1A[j] = fmaxf(a, 0.f);
        h1B[j] = fmaxf(b, 0.f);
    }

    float o0A = b3[0], o1A = b3[1];
    float o0B = o0A, o1B = o1A;
    #pragma unroll
    for (int j = 0; j < 32; j++) {
        float a = b2[j], b = a;
        #pragma unroll
        for (int k = 0; k < 32; k++) {
            float w = w2t[j * 32 + k];
            a = fmaf(h1A[k], w, a);
            b = fmaf(h1B[k], w, b);
        }
        a = fmaxf(a, 0.f);
        b = fmaxf(b, 0.f);
        float u0 = w3[2 * j + 0], u1 = w3[2 * j + 1];
        o0A = fmaf(a, u0, o0A); o1A = fmaf(a, u1, o1A);
        o0B = fmaf(b, u0, o0B); o1B = fmaf(b, u1, o1B);
    }
    int posA = rowptr[dd.x] + rk.x;
    int posB = rowptr[dd.y] + rk.y;
    he[posA] = make_float2(fmaxf(o0A, 0.f), fmaxf(o1A, 0.f));
    he[posB] = make_float2(fmaxf(o0B, 0.f), fmaxf(o1B, 0.f));
}

// mean-aggregate encoder outputs per node (contiguous CSR segment)
__global__ __launch_bounds__(256) void k_reduce_enc(const float2* __restrict__ he,
                                                    const int* __restrict__ rowptr,
                                                    const float* __restrict__ invcnt,
                                                    float2* __restrict__ agg1) {
    int i = blockIdx.x * 256 + threadIdx.x;
    if (i >= N_NODES) return;
    int p0 = rowptr[i], p1 = rowptr[i + 1];
    float a0 = 0.f, a1 = 0.f;
    for (int p = p0; p < p1; p++) {
        float2 h = he[p];
        a0 += h.x; a1 += h.y;
    }
    float ic = invcnt[i];
    agg1[i] = make_float2(a0 * ic, a1 * ic);
}

// Decoder EdgeConv per-edge MLP: 4 -> 32 -> 32 -> 4, relu on first two.
// TWO edges per thread.
__global__ __launch_bounds__(256, 4) void k_dec_edge(const float2* __restrict__ henc,
                                                     const int* __restrict__ ei,
                                                     const int* __restrict__ rowptr,
                                                     const int* __restrict__ rank,
                                                     float4* __restrict__ hd,
                                                     const float* __restrict__ v1t,
                                                     const float* __restrict__ b1,
                                                     const float* __restrict__ v2t,
                                                     const float* __restrict__ b2,
                                                     const float* __restrict__ w3,
                                                     const float* __restrict__ b3) {
    int t = blockIdx.x * 256 + threadIdx.x;
    int e0 = 2 * t;
    if (e0 >= N_EDGES) return;
    int2 ss = *(const int2*)&ei[e0];
    int2 dd = *(const int2*)&ei[N_EDGES + e0];
    int2 rk = *(const int2*)&rank[e0];
    float2 hiA = henc[dd.x];
    float2 hjA = henc[ss.x];
    float2 hiB = henc[dd.y];
    float2 hjB = henc[ss.y];
    float inA[4], inB[4];
    inA[0] = hiA.x; inA[1] = hiA.y; inA[2] = hjA.x - hiA.x; inA[3] = hjA.y - hiA.y;
    inB[0] = hiB.x; inB[1] = hiB.y; inB[2] = hjB.x - hiB.x; inB[3] = hjB.y - hiB.y;

    float h1A[32], h1B[32];
    #pragma unroll
    for (int j = 0; j < 32; j++) {
        float a = b1[j], b = a;
        #pragma unroll
        for (int k = 0; k < 4; k++) {
            float w = v1t[j * 4 + k];
            a = fmaf(inA[k], w, a);
            b = fmaf(inB[k], w, b);
        }
        h1A[j] = fmaxf(a, 0.f);
        h1B[j] = fmaxf(b, 0.f);
    }

    float o0A = b3[0], o1A = b3[1], o2A = b3[2], o3A = b3[3];
    float o0B = o0A, o1B = o1A, o2B = o2A, o3B = o3A;
    #pragma unroll
    for (int j = 0; j < 32; j++) {
        float a = b2[j], b = a;
        #pragma unroll
        for (int k = 0; k < 32; k++) {
            float w = v2t[j * 32 + k];
            a = fmaf(h1A[k], w, a);
            b = fmaf(h1B[k], w, b);
        }
        a = fmaxf(a, 0.f);
        b = fmaxf(b, 0.f);
        float u0 = w3[4 * j + 0], u1 = w3[4 * j + 1];
        float u2 = w3[4 * j + 2], u3 = w3[4 * j + 3];
        o0A = fmaf(a, u0, o0A); o1A = fmaf(a, u1, o1A);
        o2A = fmaf(a, u2, o2A); o3A = fmaf(a, u3, o3A);
        o0B = fmaf(b, u0, o0B); o1B = fmaf(b, u1, o1B);
        o2B = fmaf(b, u2, o2B); o3B = fmaf(b, u3, o3B);
    }
    int posA = rowptr[dd.x] + rk.x;
    int posB = rowptr[dd.y] + rk.y;
    hd[posA] = make_float4(o0A, o1A, o2A, o3A);  // no final relu
    hd[posB] = make_float4(o0B, o1B, o2B, o3B);
}

// mean-aggregate decoder outputs per node -> final output
__global__ __launch_bounds__(256) void k_reduce_dec(const float4* __restrict__ hd,
                                                    const int* __restrict__ rowptr,
                                                    const float* __restrict__ invcnt,
                                                    float4* __restrict__ out) {
    int i = blockIdx.x * 256 + threadIdx.x;
    if (i >= N_NODES) return;
    int p0 = rowptr[i], p1 = rowptr[i + 1];
    float a0 = 0.f, a1 = 0.f, a2 = 0.f, a3 = 0.f;
    for (int p = p0; p < p1; p++) {
        float4 h = hd[p];
        a0 += h.x; a1 += h.y; a2 += h.z; a3 += h.w;
    }
    float ic = invcnt[i];
    out[i] = make_float4(a0 * ic, a1 * ic, a2 * ic, a3 * ic);
}

extern "C" void kernel_launch(void* const* d_in, const int* in_sizes, int n_in,
                              void* d_out, int out_size, void* d_ws, size_t ws_size,
                              hipStream_t stream) {
    const float* x    = (const float*)d_in[0];
    const int*   ei   = (const int*)d_in[1];
    const float* bn_w = (const float*)d_in[2];
    const float* bn_b = (const float*)d_in[3];
    const float* ew1  = (const float*)d_in[4];
    const float* eb1  = (const float*)d_in[5];
    const float* ew2  = (const float*)d_in[6];
    const float* eb2  = (const float*)d_in[7];
    const float* ew3  = (const float*)d_in[8];
    const float* eb3  = (const float*)d_in[9];
    const float* dw1  = (const float*)d_in[10];
    const float* db1  = (const float*)d_in[11];
    const float* dw2  = (const float*)d_in[12];
    const float* db2  = (const float*)d_in[13];
    const float* dw3  = (const float*)d_in[14];
    const float* db3  = (const float*)d_in[15];

    char* ws = (char*)d_ws;
    double* stats  = (double*)(ws + OFF_STATS);
    int*    cnt    = (int*)(ws + OFF_CNT);
    int*    rowptr = (int*)(ws + OFF_ROWPTR);
    float*  invcnt = (float*)(ws + OFF_INVCNT);
    float2* agg1   = (float2*)(ws + OFF_AGG1);
    float*  xn     = (float*)(ws + OFF_XN);
    int*    rank   = (int*)(ws + OFF_RANK);
    int*    bsum   = (int*)(ws + OFF_BSUM);
    int*    boff   = (int*)(ws + OFF_BOFF);
    float*  w1t    = (float*)(ws + OFF_W1T);
    float*  w2t    = (float*)(ws + OFF_W2T);
    float*  v1t    = (float*)(ws + OFF_V1T);
    float*  v2t    = (float*)(ws + OFF_V2T);
    float2* he     = (float2*)(ws + OFF_H);
    float4* hd     = (float4*)(ws + OFF_H);   // aliased: enc reduce done before dec writes
    float4* out    = (float4*)d_out;

    // zero: stats (1 KB) + cnt (400 KB), contiguous
    hipMemsetAsync(ws, 0, OFF_CNT + N_NODES * sizeof(int), stream);

    const int edgeBlocks  = (N_EDGES + 255) / 256;        // 12500
    const int edgeBlocks2 = (N_EDGES / 2 + 255) / 256;    // 6250

    k_rank<<<edgeBlocks, 256, 0, stream>>>(ei, cnt, rank);
    k_prep<<<1, 1024, 0, stream>>>(ew1, ew2, dw1, dw2, w1t, w2t, v1t, v2t);
    k_bn_stats<<<NODE_BLOCKS, 256, 0, stream>>>(x, stats);
    k_normalize<<<NODE_BLOCKS, 256, 0, stream>>>(x, stats, bn_w, bn_b, xn);
    k_scan_part<<<NODE_BLOCKS, 256, 0, stream>>>(cnt, bsum, invcnt);
    k_scan_top<<<1, 512, 0, stream>>>(bsum, boff, rowptr);
    k_scan_local<<<NODE_BLOCKS, 256, 0, stream>>>(cnt, boff, rowptr);
    k_enc_edge<<<edgeBlocks2, 256, 0, stream>>>(xn, ei, rowptr, rank, he, w1t, eb1, w2t, eb2, ew3, eb3);
    k_reduce_enc<<<NODE_BLOCKS, 256, 0, stream>>>(he, rowptr, invcnt, agg1);
    k_dec_edge<<<edgeBlocks2, 256, 0, stream>>>(agg1, ei, rowptr, rank, hd, v1t, db1, v2t, db2, dw3, db3);
    k_reduce_dec<<<NODE_BLOCKS, 256, 0, stream>>>(hd, rowptr, invcnt, out);
}

// Round 6
// 577.787 us; speedup vs baseline: 1.0092x; 1.0092x over previous
//
#include <hip/hip_runtime.h>

#define N_NODES 100000
#define N_EDGES 3200000
#define EPS 1e-5f
#define NODE_BLOCKS 391   // ceil(100000/256)

// ---- workspace layout (bytes) ----
#define OFF_STATS  0          // 8 doubles (bn sums)                 [zeroed]
#define OFF_CNT8   1024       // int[8*100000] replicated histogram  [zeroed]
#define OFF_ROWPTR 3201024    // int[100001]
#define OFF_CNTT   3601152    // int[100000] total in-degree
#define OFF_INVCNT 4001152    // float[100000]
#define OFF_BASE8  4401152    // int[100000*8] per-node replica prefix
#define OFF_AGG1   7601152    // float2[100000] encoder node out
#define OFF_XN     8401152    // float4[100000] normalized x
#define OFF_RANK   10001152   // int[3200000] replica-local rank
#define OFF_BSUM   22801152   // int[391]
#define OFF_BOFF   22802816   // int[391]
#define OFF_W1T    22804480   // transposed weights
#define OFF_W2T    22805504
#define OFF_V1T    22809600
#define OFF_V2T    22810112
#define OFF_H      22814336   // CSR-ordered edge outputs; he(float2)/hd(float4) aliased
// total ≈ 74 MB

__global__ __launch_bounds__(256) void k_bn_stats(const float* __restrict__ x,
                                                  double* __restrict__ stats) {
    int i = blockIdx.x * 256 + threadIdx.x;
    float4 v = make_float4(0.f, 0.f, 0.f, 0.f);
    if (i < N_NODES) v = ((const float4*)x)[i];
    double a[8];
    a[0] = v.x; a[1] = v.y; a[2] = v.z; a[3] = v.w;
    a[4] = (double)v.x * v.x; a[5] = (double)v.y * v.y;
    a[6] = (double)v.z * v.z; a[7] = (double)v.w * v.w;
    #pragma unroll
    for (int off = 32; off > 0; off >>= 1) {
        #pragma unroll
        for (int j = 0; j < 8; j++) a[j] += __shfl_down(a[j], off);
    }
    __shared__ double smem[4][8];
    int wave = threadIdx.x >> 6;
    int lane = threadIdx.x & 63;
    if (lane == 0) {
        #pragma unroll
        for (int j = 0; j < 8; j++) smem[wave][j] = a[j];
    }
    __syncthreads();
    if (threadIdx.x == 0) {
        #pragma unroll
        for (int j = 0; j < 8; j++) {
            double t = smem[0][j] + smem[1][j] + smem[2][j] + smem[3][j];
            atomicAdd(&stats[j], t);
        }
    }
}

__global__ __launch_bounds__(256) void k_normalize(const float* __restrict__ x,
                                                   const double* __restrict__ stats,
                                                   const float* __restrict__ bn_w,
                                                   const float* __restrict__ bn_b,
                                                   float* __restrict__ xn) {
    int i = blockIdx.x * 256 + threadIdx.x;
    if (i >= N_NODES) return;
    const double inv_n = 1.0 / (double)N_NODES;
    float mu[4], sc[4], sh[4];
    #pragma unroll
    for (int d = 0; d < 4; d++) {
        double m  = stats[d] * inv_n;
        double vr = stats[4 + d] * inv_n - m * m;
        float rs  = (float)(1.0 / sqrt(vr + (double)EPS));
        mu[d] = (float)m;
        sc[d] = rs * bn_w[d];
        sh[d] = bn_b[d];
    }
    float4 v = ((const float4*)x)[i];
    float4 o;
    o.x = (v.x - mu[0]) * sc[0] + sh[0];
    o.y = (v.y - mu[1]) * sc[1] + sh[1];
    o.z = (v.z - mu[2]) * sc[2] + sh[2];
    o.w = (v.w - mu[3]) * sc[3] + sh[3];
    ((float4*)xn)[i] = o;
}

// transpose weights so the streaming-j MLP form reads contiguous scalar rows
__global__ __launch_bounds__(1024) void k_prep(const float* __restrict__ ew1,
                                               const float* __restrict__ ew2,
                                               const float* __restrict__ dw1,
                                               const float* __restrict__ dw2,
                                               float* __restrict__ w1t,
                                               float* __restrict__ w2t,
                                               float* __restrict__ v1t,
                                               float* __restrict__ v2t) {
    int t = threadIdx.x;
    { int j = t >> 5, k = t & 31; w2t[j * 32 + k] = ew2[k * 32 + j]; }
    { int j = t >> 5, k = t & 31; v2t[j * 32 + k] = dw2[k * 32 + j]; }
    if (t < 256) { int j = t >> 3, k = t & 7; w1t[j * 8 + k] = ew1[k * 32 + j]; }
    if (t < 128) { int j = t >> 2, k = t & 3; v1t[j * 4 + k] = dw1[k * 32 + j]; }
}

// 8-way replicated ranking: replica r = blockIdx&7 (round-robin XCD mapping).
// Each replica's counters live in their own 400 KB range -> atomic lines stay
// XCD-local instead of bouncing across 8 XCDs.
__global__ __launch_bounds__(256) void k_rank8(const int* __restrict__ ei,
                                               int* __restrict__ cnt8,
                                               int* __restrict__ rank) {
    int e = blockIdx.x * 256 + threadIdx.x;
    if (e >= N_EDGES) return;
    int r = blockIdx.x & 7;
    int d = ei[N_EDGES + e];
    rank[e] = atomicAdd(&cnt8[r * N_NODES + d], 1);
}

// scan phase A: fold 8 replicas -> base8 prefix, total cnt, invcnt, block sums
__global__ __launch_bounds__(256) void k_scan_part(const int* __restrict__ cnt8,
                                                   int* __restrict__ bsum,
                                                   float* __restrict__ invcnt,
                                                   int* __restrict__ base8,
                                                   int* __restrict__ cntt) {
    int i = blockIdx.x * 256 + threadIdx.x;
    int c = 0;
    if (i < N_NODES) {
        int pre[8];
        #pragma unroll
        for (int r = 0; r < 8; r++) { pre[r] = c; c += cnt8[r * N_NODES + i]; }
        #pragma unroll
        for (int r = 0; r < 8; r++) base8[i * 8 + r] = pre[r];
        cntt[i] = c;
        invcnt[i] = 1.0f / (float)(c > 1 ? c : 1);
    }
    int s = c;
    #pragma unroll
    for (int off = 32; off > 0; off >>= 1) s += __shfl_down(s, off);
    __shared__ int wsum[4];
    int wave = threadIdx.x >> 6, lane = threadIdx.x & 63;
    if (lane == 0) wsum[wave] = s;
    __syncthreads();
    if (threadIdx.x == 0) bsum[blockIdx.x] = wsum[0] + wsum[1] + wsum[2] + wsum[3];
}

// scan phase B: single small block scans 391 block sums -> block offsets + total
__global__ __launch_bounds__(512) void k_scan_top(const int* __restrict__ bsum,
                                                  int* __restrict__ boff,
                                                  int* __restrict__ rowptr) {
    __shared__ int sm[512];
    int t = threadIdx.x;
    int v = (t < NODE_BLOCKS) ? bsum[t] : 0;
    sm[t] = v;
    __syncthreads();
    for (int off = 1; off < 512; off <<= 1) {
        int u = (t >= off) ? sm[t - off] : 0;
        __syncthreads();
        sm[t] += u;
        __syncthreads();
    }
    if (t < NODE_BLOCKS) boff[t] = (t == 0) ? 0 : sm[t - 1];
    if (t == 511) rowptr[N_NODES] = sm[511];
}

// scan phase C: in-block exclusive scan + block offset -> rowptr
__global__ __launch_bounds__(256) void k_scan_local(const int* __restrict__ cntt,
                                                    const int* __restrict__ boff,
                                                    int* __restrict__ rowptr) {
    int i = blockIdx.x * 256 + threadIdx.x;
    int c = (i < N_NODES) ? cntt[i] : 0;
    int lane = threadIdx.x & 63;
    int wave = threadIdx.x >> 6;
    int x = c;
    #pragma unroll
    for (int off = 1; off < 64; off <<= 1) {
        int u = __shfl_up(x, off);
        if (lane >= off) x += u;
    }
    __shared__ int wsum[4];
    if (lane == 63) wsum[wave] = x;
    __syncthreads();
    int wo = 0;
    #pragma unroll
    for (int w = 0; w < 4; w++) if (w < wave) wo += wsum[w];
    if (i < N_NODES) rowptr[i] = boff[blockIdx.x] + wo + (x - c);
}

// Encoder EdgeConv per-edge MLP: 8 -> 32 -> 32 -> 2, relu x3. Streaming form.
// CSR slot = rowptr[d] + base8[d*8+r] + local rank, r = blockIdx&7.
__global__ __launch_bounds__(256, 4) void k_enc_edge(const float* __restrict__ xn,
                                                     const int* __restrict__ ei,
                                                     const int* __restrict__ rowptr,
                                                     const int* __restrict__ base8,
                                                     const int* __restrict__ rank,
                                                     float2* __restrict__ he,
                                                     const float* __restrict__ w1t,
                                                     const float* __restrict__ b1,
                                                     const float* __restrict__ w2t,
                                                     const float* __restrict__ b2,
                                                     const float* __restrict__ w3,
                                                     const float* __restrict__ b3) {
    int e = blockIdx.x * 256 + threadIdx.x;
    if (e >= N_EDGES) return;
    int s = ei[e];
    int d = ei[N_EDGES + e];
    float4 xi = ((const float4*)xn)[d];
    float4 xj = ((const float4*)xn)[s];
    float in[8];
    in[0] = xi.x; in[1] = xi.y; in[2] = xi.z; in[3] = xi.w;
    in[4] = xj.x - xi.x; in[5] = xj.y - xi.y; in[6] = xj.z - xi.z; in[7] = xj.w - xi.w;

    float h1[32];
    #pragma unroll
    for (int j = 0; j < 32; j++) {
        float a = b1[j];
        #pragma unroll
        for (int k = 0; k < 8; k++) a = fmaf(in[k], w1t[j * 8 + k], a);
        h1[j] = fmaxf(a, 0.f);
    }

    float o0 = b3[0], o1 = b3[1];
    #pragma unroll
    for (int j = 0; j < 32; j++) {
        float a = b2[j];
        #pragma unroll
        for (int k = 0; k < 32; k++) a = fmaf(h1[k], w2t[j * 32 + k], a);
        a = fmaxf(a, 0.f);
        o0 = fmaf(a, w3[2 * j + 0], o0);
        o1 = fmaf(a, w3[2 * j + 1], o1);
    }
    int r = blockIdx.x & 7;
    int pos = rowptr[d] + base8[(d << 3) | r] + rank[e];
    he[pos] = make_float2(fmaxf(o0, 0.f), fmaxf(o1, 0.f));
}

// mean-aggregate encoder outputs per node (contiguous CSR segment)
__global__ __launch_bounds__(256) void k_reduce_enc(const float2* __restrict__ he,
                                                    const int* __restrict__ rowptr,
                                                    const float* __restrict__ invcnt,
                                                    float2* __restrict__ agg1) {
    int i = blockIdx.x * 256 + threadIdx.x;
    if (i >= N_NODES) return;
    int p0 = rowptr[i], p1 = rowptr[i + 1];
    float a0 = 0.f, a1 = 0.f;
    for (int p = p0; p < p1; p++) {
        float2 h = he[p];
        a0 += h.x; a1 += h.y;
    }
    float ic = invcnt[i];
    agg1[i] = make_float2(a0 * ic, a1 * ic);
}

// Decoder EdgeConv per-edge MLP: 4 -> 32 -> 32 -> 4, relu on first two. Streaming form.
__global__ __launch_bounds__(256, 4) void k_dec_edge(const float2* __restrict__ henc,
                                                     const int* __restrict__ ei,
                                                     const int* __restrict__ rowptr,
                                                     const int* __restrict__ base8,
                                                     const int* __restrict__ rank,
                                                     float4* __restrict__ hd,
                                                     const float* __restrict__ v1t,
                                                     const float* __restrict__ b1,
                                                     const float* __restrict__ v2t,
                                                     const float* __restrict__ b2,
                                                     const float* __restrict__ w3,
                                                     const float* __restrict__ b3) {
    int e = blockIdx.x * 256 + threadIdx.x;
    if (e >= N_EDGES) return;
    int s = ei[e];
    int d = ei[N_EDGES + e];
    float2 hi = henc[d];
    float2 hj = henc[s];
    float in[4];
    in[0] = hi.x; in[1] = hi.y;
    in[2] = hj.x - hi.x; in[3] = hj.y - hi.y;

    float h1[32];
    #pragma unroll
    for (int j = 0; j < 32; j++) {
        float a = b1[j];
        #pragma unroll
        for (int k = 0; k < 4; k++) a = fmaf(in[k], v1t[j * 4 + k], a);
        h1[j] = fmaxf(a, 0.f);
    }

    float o0 = b3[0], o1 = b3[1], o2 = b3[2], o3 = b3[3];
    #pragma unroll
    for (int j = 0; j < 32; j++) {
        float a = b2[j];
        #pragma unroll
        for (int k = 0; k < 32; k++) a = fmaf(h1[k], v2t[j * 32 + k], a);
        a = fmaxf(a, 0.f);
        o0 = fmaf(a, w3[4 * j + 0], o0);
        o1 = fmaf(a, w3[4 * j + 1], o1);
        o2 = fmaf(a, w3[4 * j + 2], o2);
        o3 = fmaf(a, w3[4 * j + 3], o3);
    }
    int r = blockIdx.x & 7;
    int pos = rowptr[d] + base8[(d << 3) | r] + rank[e];
    hd[pos] = make_float4(o0, o1, o2, o3);  // no final relu
}

// mean-aggregate decoder outputs per node -> final output
__global__ __launch_bounds__(256) void k_reduce_dec(const float4* __restrict__ hd,
                                                    const int* __restrict__ rowptr,
                                                    const float* __restrict__ invcnt,
                                                    float4* __restrict__ out) {
    int i = blockIdx.x * 256 + threadIdx.x;
    if (i >= N_NODES) return;
    int p0 = rowptr[i], p1 = rowptr[i + 1];
    float a0 = 0.f, a1 = 0.f, a2 = 0.f, a3 = 0.f;
    for (int p = p0; p < p1; p++) {
        float4 h = hd[p];
        a0 += h.x; a1 += h.y; a2 += h.z; a3 += h.w;
    }
    float ic = invcnt[i];
    out[i] = make_float4(a0 * ic, a1 * ic, a2 * ic, a3 * ic);
}

extern "C" void kernel_launch(void* const* d_in, const int* in_sizes, int n_in,
                              void* d_out, int out_size, void* d_ws, size_t ws_size,
                              hipStream_t stream) {
    const float* x    = (const float*)d_in[0];
    const int*   ei   = (const int*)d_in[1];
    const float* bn_w = (const float*)d_in[2];
    const float* bn_b = (const float*)d_in[3];
    const float* ew1  = (const float*)d_in[4];
    const float* eb1  = (const float*)d_in[5];
    const float* ew2  = (const float*)d_in[6];
    const float* eb2  = (const float*)d_in[7];
    const float* ew3  = (const float*)d_in[8];
    const float* eb3  = (const float*)d_in[9];
    const float* dw1  = (const float*)d_in[10];
    const float* db1  = (const float*)d_in[11];
    const float* dw2  = (const float*)d_in[12];
    const float* db2  = (const float*)d_in[13];
    const float* dw3  = (const float*)d_in[14];
    const float* db3  = (const float*)d_in[15];

    char* ws = (char*)d_ws;
    double* stats  = (double*)(ws + OFF_STATS);
    int*    cnt8   = (int*)(ws + OFF_CNT8);
    int*    rowptr = (int*)(ws + OFF_ROWPTR);
    int*    cntt   = (int*)(ws + OFF_CNTT);
    float*  invcnt = (float*)(ws + OFF_INVCNT);
    int*    base8  = (int*)(ws + OFF_BASE8);
    float2* agg1   = (float2*)(ws + OFF_AGG1);
    float*  xn     = (float*)(ws + OFF_XN);
    int*    rank   = (int*)(ws + OFF_RANK);
    int*    bsum   = (int*)(ws + OFF_BSUM);
    int*    boff   = (int*)(ws + OFF_BOFF);
    float*  w1t    = (float*)(ws + OFF_W1T);
    float*  w2t    = (float*)(ws + OFF_W2T);
    float*  v1t    = (float*)(ws + OFF_V1T);
    float*  v2t    = (float*)(ws + OFF_V2T);
    float2* he     = (float2*)(ws + OFF_H);
    float4* hd     = (float4*)(ws + OFF_H);   // aliased: enc reduce done before dec writes
    float4* out    = (float4*)d_out;

    // zero: stats (1 KB) + cnt8 (3.2 MB), contiguous
    hipMemsetAsync(ws, 0, OFF_CNT8 + 8 * N_NODES * sizeof(int), stream);

    const int edgeBlocks = (N_EDGES + 255) / 256;   // 12500

    k_rank8<<<edgeBlocks, 256, 0, stream>>>(ei, cnt8, rank);
    k_prep<<<1, 1024, 0, stream>>>(ew1, ew2, dw1, dw2, w1t, w2t, v1t, v2t);
    k_bn_stats<<<NODE_BLOCKS, 256, 0, stream>>>(x, stats);
    k_normalize<<<NODE_BLOCKS, 256, 0, stream>>>(x, stats, bn_w, bn_b, xn);
    k_scan_part<<<NODE_BLOCKS, 256, 0, stream>>>(cnt8, bsum, invcnt, base8, cntt);
    k_scan_top<<<1, 512, 0, stream>>>(bsum, boff, rowptr);
    k_scan_local<<<NODE_BLOCKS, 256, 0, stream>>>(cntt, boff, rowptr);
    k_enc_edge<<<edgeBlocks, 256, 0, stream>>>(xn, ei, rowptr, base8, rank, he, w1t, eb1, w2t, eb2, ew3, eb3);
    k_reduce_enc<<<NODE_BLOCKS, 256, 0, stream>>>(he, rowptr, invcnt, agg1);
    k_dec_edge<<<edgeBlocks, 256, 0, stream>>>(agg1, ei, rowptr, base8, rank, hd, v1t, db1, v2t, db2, dw3, db3);
    k_reduce_dec<<<NODE_BLOCKS, 256, 0, stream>>>(hd, rowptr, invcnt, out);
}

// Round 7
// 467.944 us; speedup vs baseline: 1.2461x; 1.2347x over previous
//
#include <hip/hip_runtime.h>

#define N_NODES 100000
#define N_EDGES 3200000
#define EPS 1e-5f
#define NODE_BLOCKS 391   // ceil(100000/256)

typedef float v2f __attribute__((ext_vector_type(2)));
static __device__ __forceinline__ v2f splat(float x) { v2f v; v.x = x; v.y = x; return v; }

// ---- workspace layout (bytes) ----
#define OFF_STATS   0          // 8 doubles (bn sums)        [zeroed]
#define OFF_CNT     1024       // int[100000] in-degree      [zeroed]
#define OFF_ROWPTR  401024     // int[100001]
#define OFF_INVCNT  801152     // float[100000]
#define OFF_XN      1201152    // float4[100000]
#define OFF_AGG1    2801152    // float2[100000]
#define OFF_RANK    3601152    // int[3200000]
#define OFF_BSUM    16401152   // int[391]
#define OFF_BOFF    16403200   // int[391]
#define OFF_W1T     16405248   // transposed weights
#define OFF_W2T     16406272
#define OFF_V1T     16410368
#define OFF_V2T     16410880
#define OFF_HE_EDGE 16415232   // float2[3200000] enc out, edge order
#define OFF_HE_CSR  42015232   // float2[3200000] enc out, CSR order
// hd (float4[3200000]) aliases OFF_HE_EDGE..+51.2MB (both he buffers consumed first)
#define OFF_HD      16415232
// total ≈ 67.6 MB

__global__ __launch_bounds__(256) void k_bn_stats(const float* __restrict__ x,
                                                  double* __restrict__ stats) {
    int i = blockIdx.x * 256 + threadIdx.x;
    float4 v = make_float4(0.f, 0.f, 0.f, 0.f);
    if (i < N_NODES) v = ((const float4*)x)[i];
    double a[8];
    a[0] = v.x; a[1] = v.y; a[2] = v.z; a[3] = v.w;
    a[4] = (double)v.x * v.x; a[5] = (double)v.y * v.y;
    a[6] = (double)v.z * v.z; a[7] = (double)v.w * v.w;
    #pragma unroll
    for (int off = 32; off > 0; off >>= 1) {
        #pragma unroll
        for (int j = 0; j < 8; j++) a[j] += __shfl_down(a[j], off);
    }
    __shared__ double smem[4][8];
    int wave = threadIdx.x >> 6;
    int lane = threadIdx.x & 63;
    if (lane == 0) {
        #pragma unroll
        for (int j = 0; j < 8; j++) smem[wave][j] = a[j];
    }
    __syncthreads();
    if (threadIdx.x == 0) {
        #pragma unroll
        for (int j = 0; j < 8; j++) {
            double t = smem[0][j] + smem[1][j] + smem[2][j] + smem[3][j];
            atomicAdd(&stats[j], t);
        }
    }
}

__global__ __launch_bounds__(256) void k_normalize(const float* __restrict__ x,
                                                   const double* __restrict__ stats,
                                                   const float* __restrict__ bn_w,
                                                   const float* __restrict__ bn_b,
                                                   float* __restrict__ xn) {
    int i = blockIdx.x * 256 + threadIdx.x;
    if (i >= N_NODES) return;
    const double inv_n = 1.0 / (double)N_NODES;
    float mu[4], sc[4], sh[4];
    #pragma unroll
    for (int d = 0; d < 4; d++) {
        double m  = stats[d] * inv_n;
        double vr = stats[4 + d] * inv_n - m * m;
        float rs  = (float)(1.0 / sqrt(vr + (double)EPS));
        mu[d] = (float)m;
        sc[d] = rs * bn_w[d];
        sh[d] = bn_b[d];
    }
    float4 v = ((const float4*)x)[i];
    float4 o;
    o.x = (v.x - mu[0]) * sc[0] + sh[0];
    o.y = (v.y - mu[1]) * sc[1] + sh[1];
    o.z = (v.z - mu[2]) * sc[2] + sh[2];
    o.w = (v.w - mu[3]) * sc[3] + sh[3];
    ((float4*)xn)[i] = o;
}

// transpose weights so the streaming-j MLP form reads contiguous scalar rows
__global__ __launch_bounds__(1024) void k_prep(const float* __restrict__ ew1,
                                               const float* __restrict__ ew2,
                                               const float* __restrict__ dw1,
                                               const float* __restrict__ dw2,
                                               float* __restrict__ w1t,
                                               float* __restrict__ w2t,
                                               float* __restrict__ v1t,
                                               float* __restrict__ v2t) {
    int t = threadIdx.x;
    { int j = t >> 5, k = t & 31; w2t[j * 32 + k] = ew2[k * 32 + j]; }
    { int j = t >> 5, k = t & 31; v2t[j * 32 + k] = dw2[k * 32 + j]; }
    if (t < 256) { int j = t >> 3, k = t & 7; w1t[j * 8 + k] = ew1[k * 32 + j]; }
    if (t < 128) { int j = t >> 2, k = t & 3; v1t[j * 4 + k] = dw1[k * 32 + j]; }
}

// Encoder EdgeConv per-edge MLP (8->32->32->2, relu x3), 2 edges/thread via
// packed fp32 (v_pk_fma_f32): x-lane = edge A, y-lane = edge B.
// Also performs the rank atomics (latency hidden under the MLP), writes
// he_edge coalesced in edge order.
__global__ __launch_bounds__(256, 4) void k_enc_edge(const float* __restrict__ xn,
                                                     const int* __restrict__ ei,
                                                     int* __restrict__ cnt,
                                                     int* __restrict__ rank,
                                                     float2* __restrict__ he_edge,
                                                     const float* __restrict__ w1t,
                                                     const float* __restrict__ b1,
                                                     const float* __restrict__ w2t,
                                                     const float* __restrict__ b2,
                                                     const float* __restrict__ w3,
                                                     const float* __restrict__ b3) {
    int t = blockIdx.x * 256 + threadIdx.x;
    int e0 = 2 * t;
    if (e0 >= N_EDGES) return;   // N_EDGES even
    int2 ss = *(const int2*)&ei[e0];
    int2 dd = *(const int2*)&ei[N_EDGES + e0];
    // rank atomics issued early; results not needed until the very end
    int rA = atomicAdd(&cnt[dd.x], 1);
    int rB = atomicAdd(&cnt[dd.y], 1);
    float4 xiA = ((const float4*)xn)[dd.x];
    float4 xjA = ((const float4*)xn)[ss.x];
    float4 xiB = ((const float4*)xn)[dd.y];
    float4 xjB = ((const float4*)xn)[ss.y];
    v2f in[8];
    in[0].x = xiA.x; in[0].y = xiB.x;
    in[1].x = xiA.y; in[1].y = xiB.y;
    in[2].x = xiA.z; in[2].y = xiB.z;
    in[3].x = xiA.w; in[3].y = xiB.w;
    in[4].x = xjA.x - xiA.x; in[4].y = xjB.x - xiB.x;
    in[5].x = xjA.y - xiA.y; in[5].y = xjB.y - xiB.y;
    in[6].x = xjA.z - xiA.z; in[6].y = xjB.z - xiB.z;
    in[7].x = xjA.w - xiA.w; in[7].y = xjB.w - xiB.w;

    v2f h1[32];
    #pragma unroll
    for (int j = 0; j < 32; j++) {
        v2f a = splat(b1[j]);
        #pragma unroll
        for (int k = 0; k < 8; k++) a = __builtin_elementwise_fma(in[k], splat(w1t[j * 8 + k]), a);
        h1[j] = __builtin_elementwise_max(a, splat(0.f));
    }

    v2f o0 = splat(b3[0]), o1 = splat(b3[1]);
    #pragma unroll
    for (int j = 0; j < 32; j++) {
        v2f a = splat(b2[j]);
        #pragma unroll
        for (int k = 0; k < 32; k++) a = __builtin_elementwise_fma(h1[k], splat(w2t[j * 32 + k]), a);
        a = __builtin_elementwise_max(a, splat(0.f));
        o0 = __builtin_elementwise_fma(a, splat(w3[2 * j + 0]), o0);
        o1 = __builtin_elementwise_fma(a, splat(w3[2 * j + 1]), o1);
    }
    o0 = __builtin_elementwise_max(o0, splat(0.f));
    o1 = __builtin_elementwise_max(o1, splat(0.f));
    ((float4*)he_edge)[t] = make_float4(o0.x, o1.x, o0.y, o1.y);
    *(int2*)&rank[e0] = make_int2(rA, rB);
}

// scan phase A: per-block sums of cnt; also invcnt
__global__ __launch_bounds__(256) void k_scan_part(const int* __restrict__ cnt,
                                                   int* __restrict__ bsum,
                                                   float* __restrict__ invcnt) {
    int i = blockIdx.x * 256 + threadIdx.x;
    int c = (i < N_NODES) ? cnt[i] : 0;
    if (i < N_NODES) invcnt[i] = 1.0f / (float)(c > 1 ? c : 1);
    int s = c;
    #pragma unroll
    for (int off = 32; off > 0; off >>= 1) s += __shfl_down(s, off);
    __shared__ int wsum[4];
    int wave = threadIdx.x >> 6, lane = threadIdx.x & 63;
    if (lane == 0) wsum[wave] = s;
    __syncthreads();
    if (threadIdx.x == 0) bsum[blockIdx.x] = wsum[0] + wsum[1] + wsum[2] + wsum[3];
}

// scan phase B: single small block scans 391 block sums -> block offsets + total
__global__ __launch_bounds__(512) void k_scan_top(const int* __restrict__ bsum,
                                                  int* __restrict__ boff,
                                                  int* __restrict__ rowptr) {
    __shared__ int sm[512];
    int t = threadIdx.x;
    int v = (t < NODE_BLOCKS) ? bsum[t] : 0;
    sm[t] = v;
    __syncthreads();
    for (int off = 1; off < 512; off <<= 1) {
        int u = (t >= off) ? sm[t - off] : 0;
        __syncthreads();
        sm[t] += u;
        __syncthreads();
    }
    if (t < NODE_BLOCKS) boff[t] = (t == 0) ? 0 : sm[t - 1];
    if (t == 511) rowptr[N_NODES] = sm[511];
}

// scan phase C: in-block exclusive scan + block offset -> rowptr
__global__ __launch_bounds__(256) void k_scan_local(const int* __restrict__ cnt,
                                                    const int* __restrict__ boff,
                                                    int* __restrict__ rowptr) {
    int i = blockIdx.x * 256 + threadIdx.x;
    int c = (i < N_NODES) ? cnt[i] : 0;
    int lane = threadIdx.x & 63;
    int wave = threadIdx.x >> 6;
    int x = c;
    #pragma unroll
    for (int off = 1; off < 64; off <<= 1) {
        int u = __shfl_up(x, off);
        if (lane >= off) x += u;
    }
    __shared__ int wsum[4];
    if (lane == 63) wsum[wave] = x;
    __syncthreads();
    int wo = 0;
    #pragma unroll
    for (int w = 0; w < 4; w++) if (w < wave) wo += wsum[w];
    if (i < N_NODES) rowptr[i] = boff[blockIdx.x] + wo + (x - c);
}

// move enc outputs from edge order into CSR slots (streamed, no atomics)
__global__ __launch_bounds__(256) void k_place(const float2* __restrict__ he_edge,
                                               const int* __restrict__ ei,
                                               const int* __restrict__ rowptr,
                                               const int* __restrict__ rank,
                                               float2* __restrict__ he_csr) {
    int e = blockIdx.x * 256 + threadIdx.x;
    if (e >= N_EDGES) return;
    int d = ei[N_EDGES + e];
    he_csr[rowptr[d] + rank[e]] = he_edge[e];
}

// mean-aggregate encoder outputs per node (contiguous CSR segment)
__global__ __launch_bounds__(256) void k_reduce_enc(const float2* __restrict__ he,
                                                    const int* __restrict__ rowptr,
                                                    const float* __restrict__ invcnt,
                                                    float2* __restrict__ agg1) {
    int i = blockIdx.x * 256 + threadIdx.x;
    if (i >= N_NODES) return;
    int p0 = rowptr[i], p1 = rowptr[i + 1];
    float a0 = 0.f, a1 = 0.f;
    for (int p = p0; p < p1; p++) {
        float2 h = he[p];
        a0 += h.x; a1 += h.y;
    }
    float ic = invcnt[i];
    agg1[i] = make_float2(a0 * ic, a1 * ic);
}

// Decoder EdgeConv per-edge MLP (4->32->32->4, relu first two), 2 edges/thread
// packed fp32. Writes directly to CSR slots.
__global__ __launch_bounds__(256, 4) void k_dec_edge(const float2* __restrict__ henc,
                                                     const int* __restrict__ ei,
                                                     const int* __restrict__ rowptr,
                                                     const int* __restrict__ rank,
                                                     float4* __restrict__ hd,
                                                     const float* __restrict__ v1t,
                                                     const float* __restrict__ b1,
                                                     const float* __restrict__ v2t,
                                                     const float* __restrict__ b2,
                                                     const float* __restrict__ w3,
                                                     const float* __restrict__ b3) {
    int t = blockIdx.x * 256 + threadIdx.x;
    int e0 = 2 * t;
    if (e0 >= N_EDGES) return;
    int2 ss = *(const int2*)&ei[e0];
    int2 dd = *(const int2*)&ei[N_EDGES + e0];
    int2 rk = *(const int2*)&rank[e0];
    float2 hiA = henc[dd.x];
    float2 hjA = henc[ss.x];
    float2 hiB = henc[dd.y];
    float2 hjB = henc[ss.y];
    v2f in[4];
    in[0].x = hiA.x;         in[0].y = hiB.x;
    in[1].x = hiA.y;         in[1].y = hiB.y;
    in[2].x = hjA.x - hiA.x; in[2].y = hjB.x - hiB.x;
    in[3].x = hjA.y - hiA.y; in[3].y = hjB.y - hiB.y;

    v2f h1[32];
    #pragma unroll
    for (int j = 0; j < 32; j++) {
        v2f a = splat(b1[j]);
        #pragma unroll
        for (int k = 0; k < 4; k++) a = __builtin_elementwise_fma(in[k], splat(v1t[j * 4 + k]), a);
        h1[j] = __builtin_elementwise_max(a, splat(0.f));
    }

    v2f o0 = splat(b3[0]), o1 = splat(b3[1]), o2 = splat(b3[2]), o3 = splat(b3[3]);
    #pragma unroll
    for (int j = 0; j < 32; j++) {
        v2f a = splat(b2[j]);
        #pragma unroll
        for (int k = 0; k < 32; k++) a = __builtin_elementwise_fma(h1[k], splat(v2t[j * 32 + k]), a);
        a = __builtin_elementwise_max(a, splat(0.f));
        o0 = __builtin_elementwise_fma(a, splat(w3[4 * j + 0]), o0);
        o1 = __builtin_elementwise_fma(a, splat(w3[4 * j + 1]), o1);
        o2 = __builtin_elementwise_fma(a, splat(w3[4 * j + 2]), o2);
        o3 = __builtin_elementwise_fma(a, splat(w3[4 * j + 3]), o3);
    }
    int posA = rowptr[dd.x] + rk.x;
    int posB = rowptr[dd.y] + rk.y;
    hd[posA] = make_float4(o0.x, o1.x, o2.x, o3.x);  // no final relu
    hd[posB] = make_float4(o0.y, o1.y, o2.y, o3.y);
}

// mean-aggregate decoder outputs per node -> final output
__global__ __launch_bounds__(256) void k_reduce_dec(const float4* __restrict__ hd,
                                                    const int* __restrict__ rowptr,
                                                    const float* __restrict__ invcnt,
                                                    float4* __restrict__ out) {
    int i = blockIdx.x * 256 + threadIdx.x;
    if (i >= N_NODES) return;
    int p0 = rowptr[i], p1 = rowptr[i + 1];
    float a0 = 0.f, a1 = 0.f, a2 = 0.f, a3 = 0.f;
    for (int p = p0; p < p1; p++) {
        float4 h = hd[p];
        a0 += h.x; a1 += h.y; a2 += h.z; a3 += h.w;
    }
    float ic = invcnt[i];
    out[i] = make_float4(a0 * ic, a1 * ic, a2 * ic, a3 * ic);
}

extern "C" void kernel_launch(void* const* d_in, const int* in_sizes, int n_in,
                              void* d_out, int out_size, void* d_ws, size_t ws_size,
                              hipStream_t stream) {
    const float* x    = (const float*)d_in[0];
    const int*   ei   = (const int*)d_in[1];
    const float* bn_w = (const float*)d_in[2];
    const float* bn_b = (const float*)d_in[3];
    const float* ew1  = (const float*)d_in[4];
    const float* eb1  = (const float*)d_in[5];
    const float* ew2  = (const float*)d_in[6];
    const float* eb2  = (const float*)d_in[7];
    const float* ew3  = (const float*)d_in[8];
    const float* eb3  = (const float*)d_in[9];
    const float* dw1  = (const float*)d_in[10];
    const float* db1  = (const float*)d_in[11];
    const float* dw2  = (const float*)d_in[12];
    const float* db2  = (const float*)d_in[13];
    const float* dw3  = (const float*)d_in[14];
    const float* db3  = (const float*)d_in[15];

    char* ws = (char*)d_ws;
    double* stats   = (double*)(ws + OFF_STATS);
    int*    cnt     = (int*)(ws + OFF_CNT);
    int*    rowptr  = (int*)(ws + OFF_ROWPTR);
    float*  invcnt  = (float*)(ws + OFF_INVCNT);
    float*  xn      = (float*)(ws + OFF_XN);
    float2* agg1    = (float2*)(ws + OFF_AGG1);
    int*    rank    = (int*)(ws + OFF_RANK);
    int*    bsum    = (int*)(ws + OFF_BSUM);
    int*    boff    = (int*)(ws + OFF_BOFF);
    float*  w1t     = (float*)(ws + OFF_W1T);
    float*  w2t     = (float*)(ws + OFF_W2T);
    float*  v1t     = (float*)(ws + OFF_V1T);
    float*  v2t     = (float*)(ws + OFF_V2T);
    float2* he_edge = (float2*)(ws + OFF_HE_EDGE);
    float2* he_csr  = (float2*)(ws + OFF_HE_CSR);
    float4* hd      = (float4*)(ws + OFF_HD);   // aliases he buffers (consumed first)
    float4* out     = (float4*)d_out;

    // zero: stats (1 KB) + cnt (400 KB), contiguous
    hipMemsetAsync(ws, 0, OFF_CNT + N_NODES * sizeof(int), stream);

    const int edgeBlocks  = (N_EDGES + 255) / 256;        // 12500
    const int edgeBlocks2 = (N_EDGES / 2 + 255) / 256;    // 6250

    k_prep<<<1, 1024, 0, stream>>>(ew1, ew2, dw1, dw2, w1t, w2t, v1t, v2t);
    k_bn_stats<<<NODE_BLOCKS, 256, 0, stream>>>(x, stats);
    k_normalize<<<NODE_BLOCKS, 256, 0, stream>>>(x, stats, bn_w, bn_b, xn);
    k_enc_edge<<<edgeBlocks2, 256, 0, stream>>>(xn, ei, cnt, rank, he_edge,
                                                w1t, eb1, w2t, eb2, ew3, eb3);
    k_scan_part<<<NODE_BLOCKS, 256, 0, stream>>>(cnt, bsum, invcnt);
    k_scan_top<<<1, 512, 0, stream>>>(bsum, boff, rowptr);
    k_scan_local<<<NODE_BLOCKS, 256, 0, stream>>>(cnt, boff, rowptr);
    k_place<<<edgeBlocks, 256, 0, stream>>>(he_edge, ei, rowptr, rank, he_csr);
    k_reduce_enc<<<NODE_BLOCKS, 256, 0, stream>>>(he_csr, rowptr, invcnt, agg1);
    k_dec_edge<<<edgeBlocks2, 256, 0, stream>>>(agg1, ei, rowptr, rank, hd,
                                                v1t, db1, v2t, db2, dw3, db3);
    k_reduce_dec<<<NODE_BLOCKS, 256, 0, stream>>>(hd, rowptr, invcnt, out);
}